// Round 10
// baseline (161.194 us; speedup 1.0000x reference)
//
#include <hip/hip_runtime.h>
#include <math.h>

// Problem constants: src (N,C,D,H,W) = (2,1,160,192,160) fp32
#define N_ 2
#define D_ 160
#define H_ 192
#define W_ 160
#define HW_ (H_*W_)              // 30,720
#define DHW_ (D_*H_*W_)          // 4,915,200
#define TOTAL_ (N_*DHW_)         // 9,830,400
#define BLOCKS_PER_N_ (DHW_/256) // 19,200
#define NWG_ (TOTAL_/256)        // 38,400 (divisible by 8)
#define NXCD_ 8

__device__ __forceinline__ void matmul3(const float A[3][3], const float B[3][3], float C[3][3]) {
    #pragma unroll
    for (int i = 0; i < 3; ++i)
        #pragma unroll
        for (int j = 0; j < 3; ++j)
            C[i][j] = A[i][0]*B[0][j] + A[i][1]*B[1][j] + A[i][2]*B[2][j];
}

// Builds mat (N,3,4) into the tail of d_out (tuple output #2).
__global__ void build_mat_kernel(const float* __restrict__ affine,
                                 const float* __restrict__ scale,
                                 const float* __restrict__ translate,
                                 const float* __restrict__ shear,
                                 float* __restrict__ mat_out) {
    int n = threadIdx.x;
    if (n >= N_) return;
    float tx = affine[n*3+0], ty = affine[n*3+1], tz = affine[n*3+2];
    float sx = scale[n*3+0],  sy = scale[n*3+1],  sz = scale[n*3+2];
    float t_xy = tanf(shear[n*6+0]), t_xz = tanf(shear[n*6+1]);
    float t_yx = tanf(shear[n*6+2]), t_yz = tanf(shear[n*6+3]);
    float t_zx = tanf(shear[n*6+4]), t_zy = tanf(shear[n*6+5]);
    float cx = cosf(tx), sxv = sinf(tx);
    float cy = cosf(ty), syv = sinf(ty);
    float cz = cosf(tz), szv = sinf(tz);
    float RX[3][3] = {{1,0,0},{0,cx,sxv},{0,-sxv,cx}};
    float RY[3][3] = {{cy,0,-syv},{0,1,0},{syv,0,cy}};
    float RZ[3][3] = {{cz,szv,0},{-szv,cz,0},{0,0,1}};
    float SC[3][3] = {{sx,0,0},{0,sy,0},{0,0,sz}};
    float SH[3][3] = {{1,t_yx,t_zx},{t_xy,1,t_zy},{t_xz,t_yz,1}};
    float M1[3][3], M2[3][3], M3[3][3], M4[3][3];
    matmul3(RY, RX, M1);
    matmul3(RZ, M1, M2);
    matmul3(SC, M2, M3);
    matmul3(SH, M3, M4);
    #pragma unroll
    for (int i = 0; i < 3; ++i) {
        #pragma unroll
        for (int j = 0; j < 3; ++j)
            mat_out[n*12 + i*4 + j] = M4[i][j];
        mat_out[n*12 + i*4 + 3] = translate[n*3 + i];
    }
}

__global__ __launch_bounds__(256)
void affine_sample_kernel(const float* __restrict__ src,
                          const float* __restrict__ mat,   // tail of d_out
                          float* __restrict__ out) {
    // XCD-chunked swizzle (R1: FETCH 85->19MB; keep). 38400 % 8 == 0.
    int bid = blockIdx.x;
    int swz = (bid & (NXCD_-1)) * (NWG_/NXCD_) + (bid >> 3);

    int n     = swz / BLOCKS_PER_N_;            // wave-uniform
    int local = (swz % BLOCKS_PER_N_) * 256 + threadIdx.x;

    int w = local % W_;
    int t = local / W_;
    int h = t % H_;
    int d = t / H_;

    const float* m = mat + n * 12;

    float x = -1.0f + w * (2.0f / (W_ - 1));
    float y = -1.0f + h * (2.0f / (H_ - 1));
    float z = -1.0f + d * (2.0f / (D_ - 1));

    float gx = m[0]*x + m[1]*y + m[2]*z  + m[3];
    float gy = m[4]*x + m[5]*y + m[6]*z  + m[7];
    float gz = m[8]*x + m[9]*y + m[10]*z + m[11];

    float ix = (gx + 1.0f) * (0.5f * (W_ - 1));
    float iy = (gy + 1.0f) * (0.5f * (H_ - 1));
    float iz = (gz + 1.0f) * (0.5f * (D_ - 1));

    float fx = floorf(ix), fy = floorf(iy), fz = floorf(iz);
    float wx = ix - fx, wy = iy - fy, wz = iz - fz;
    int x0 = (int)fx, y0 = (int)fy, z0 = (int)fz;

    // Per-axis validity masks (valid = vx*vy*vz is separable; masking value
    // by mx, c*=my after y-lerp, c*=mz after z-lerp == reference sum of
    // weight*valid*gather, exactly).
    float mx0 = ((unsigned)(x0    ) < (unsigned)W_) ? 1.0f : 0.0f;
    float mx1 = ((unsigned)(x0 + 1) < (unsigned)W_) ? 1.0f : 0.0f;
    float my0 = ((unsigned)(y0    ) < (unsigned)H_) ? 1.0f : 0.0f;
    float my1 = ((unsigned)(y0 + 1) < (unsigned)H_) ? 1.0f : 0.0f;
    float mz0 = ((unsigned)(z0    ) < (unsigned)D_) ? 1.0f : 0.0f;
    float mz1 = ((unsigned)(z0 + 1) < (unsigned)D_) ? 1.0f : 0.0f;

    // Clamped row addresses. x-pair is based at xbase in [0, W-2]; the two
    // elements [xbase, xbase+1] cover all valid x0/x1 cases via selects:
    //   x0 in [0,158]: lo = x0        -> v000=lo; v001=hi (x1=x0+1)
    //   x0 == 159    : hi = 159       -> v000=hi; x1=160 masked (mx1=0)
    //   x0 == -1     : lo = 0 == x1   -> v001=lo; x0 masked (mx0=0)
    //   x0 < -1 or > 159: both masked -> values irrelevant
    int xbase = min(max(x0, 0), W_ - 2);
    int yc0 = min(max(y0,     0), H_ - 1), yc1 = min(max(y0 + 1, 0), H_ - 1);
    int zc0 = min(max(z0,     0), D_ - 1), zc1 = min(max(z0 + 1, 0), D_ - 1);

    const float* s = src + n * DHW_;
    const float* pr00 = s + (zc0 * H_ + yc0) * W_ + xbase;
    const float* pr01 = s + (zc0 * H_ + yc1) * W_ + xbase;
    const float* pr10 = s + (zc1 * H_ + yc0) * W_ + xbase;
    const float* pr11 = s + (zc1 * H_ + yc1) * W_ + xbase;

    // Force-batched gathers: compiler kept VGPR=12 and serialized these into
    // ~2-deep batches for 3 rounds straight (R1/R3/R4 all ~70us, 1120cy/wave).
    // One asm block = 8 loads in flight, ONE vmcnt drain per wave.
    float l00, h00, l01, h01, l10, h10, l11, h11;
    asm volatile(
        "global_load_dword %0, %8, off\n\t"
        "global_load_dword %1, %8, off offset:4\n\t"
        "global_load_dword %2, %9, off\n\t"
        "global_load_dword %3, %9, off offset:4\n\t"
        "global_load_dword %4, %10, off\n\t"
        "global_load_dword %5, %10, off offset:4\n\t"
        "global_load_dword %6, %11, off\n\t"
        "global_load_dword %7, %11, off offset:4\n\t"
        "s_waitcnt vmcnt(0)"
        : "=&v"(l00), "=&v"(h00), "=&v"(l01), "=&v"(h01),
          "=&v"(l10), "=&v"(h10), "=&v"(l11), "=&v"(h11)
        : "v"(pr00), "v"(pr01), "v"(pr10), "v"(pr11));

    bool selHi = (x0 > W_ - 2);   // x0==159: element @159 is the hi slot
    bool selLo = (x0 < 0);        // x0==-1 : x1==0 is the lo slot
    float v000 = selHi ? h00 : l00,  v001 = selLo ? l00 : h00;
    float v010 = selHi ? h01 : l01,  v011 = selLo ? l01 : h01;
    float v100 = selHi ? h10 : l10,  v101 = selLo ? l10 : h10;
    float v110 = selHi ? h11 : l11,  v111 = selLo ? l11 : h11;

    float a, b;
    a = v000 * mx0; b = v001 * mx1; float c00 = a + wx * (b - a);
    a = v010 * mx0; b = v011 * mx1; float c01 = a + wx * (b - a);
    a = v100 * mx0; b = v101 * mx1; float c10 = a + wx * (b - a);
    a = v110 * mx0; b = v111 * mx1; float c11 = a + wx * (b - a);
    c00 *= my0; c01 *= my1; c10 *= my0; c11 *= my1;
    float c0 = c00 + wy * (c01 - c00);
    float c1 = c10 + wy * (c11 - c10);
    c0 *= mz0; c1 *= mz1;
    float acc = c0 + wz * (c1 - c0);

    out[n * DHW_ + local] = acc;
}

extern "C" void kernel_launch(void* const* d_in, const int* in_sizes, int n_in,
                              void* d_out, int out_size, void* d_ws, size_t ws_size,
                              hipStream_t stream) {
    const float* src       = (const float*)d_in[0];
    const float* affine    = (const float*)d_in[1];
    const float* scale     = (const float*)d_in[2];
    const float* translate = (const float*)d_in[3];
    const float* shear     = (const float*)d_in[4];

    float* out     = (float*)d_out;
    float* mat_out = out + TOTAL_;   // tuple output #2: (N,3,4) flat

    build_mat_kernel<<<1, 64, 0, stream>>>(affine, scale, translate, shear, mat_out);
    affine_sample_kernel<<<NWG_, 256, 0, stream>>>(src, mat_out, out);
}

// Round 13
// 141.238 us; speedup vs baseline: 1.1413x; 1.1413x over previous
//
#include <hip/hip_runtime.h>
#include <math.h>

// Problem constants: src (N,C,D,H,W) = (2,1,160,192,160) fp32
#define N_ 2
#define D_ 160
#define H_ 192
#define W_ 160
#define HW_ (H_*W_)              // 30,720
#define DHW_ (D_*H_*W_)          // 4,915,200
#define TOTAL_ (N_*DHW_)         // 9,830,400
#define OPB_ 512                 // outputs per block (2 per thread)
#define NWG_ (TOTAL_/OPB_)       // 19,200 (divisible by 8; 512 | DHW_ so no n-straddle)
#define NXCD_ 8

__device__ __forceinline__ void matmul3(const float A[3][3], const float B[3][3], float C[3][3]) {
    #pragma unroll
    for (int i = 0; i < 3; ++i)
        #pragma unroll
        for (int j = 0; j < 3; ++j)
            C[i][j] = A[i][0]*B[0][j] + A[i][1]*B[1][j] + A[i][2]*B[2][j];
}

// Builds mat (N,3,4) into the tail of d_out (tuple output #2).
__global__ void build_mat_kernel(const float* __restrict__ affine,
                                 const float* __restrict__ scale,
                                 const float* __restrict__ translate,
                                 const float* __restrict__ shear,
                                 float* __restrict__ mat_out) {
    int n = threadIdx.x;
    if (n >= N_) return;
    float tx = affine[n*3+0], ty = affine[n*3+1], tz = affine[n*3+2];
    float sx = scale[n*3+0],  sy = scale[n*3+1],  sz = scale[n*3+2];
    float t_xy = tanf(shear[n*6+0]), t_xz = tanf(shear[n*6+1]);
    float t_yx = tanf(shear[n*6+2]), t_yz = tanf(shear[n*6+3]);
    float t_zx = tanf(shear[n*6+4]), t_zy = tanf(shear[n*6+5]);
    float cx = cosf(tx), sxv = sinf(tx);
    float cy = cosf(ty), syv = sinf(ty);
    float cz = cosf(tz), szv = sinf(tz);
    float RX[3][3] = {{1,0,0},{0,cx,sxv},{0,-sxv,cx}};
    float RY[3][3] = {{cy,0,-syv},{0,1,0},{syv,0,cy}};
    float RZ[3][3] = {{cz,szv,0},{-szv,cz,0},{0,0,1}};
    float SC[3][3] = {{sx,0,0},{0,sy,0},{0,0,sz}};
    float SH[3][3] = {{1,t_yx,t_zx},{t_xy,1,t_zy},{t_xz,t_yz,1}};
    float M1[3][3], M2[3][3], M3[3][3], M4[3][3];
    matmul3(RY, RX, M1);
    matmul3(RZ, M1, M2);
    matmul3(SC, M2, M3);
    matmul3(SH, M3, M4);
    #pragma unroll
    for (int i = 0; i < 3; ++i) {
        #pragma unroll
        for (int j = 0; j < 3; ++j)
            mat_out[n*12 + i*4 + j] = M4[i][j];
        mat_out[n*12 + i*4 + 3] = translate[n*3 + i];
    }
}

__global__ __launch_bounds__(256)
void affine_sample_kernel(const float* __restrict__ src,
                          const float* __restrict__ mat,   // tail of d_out
                          float* __restrict__ out) {
    // XCD-chunked swizzle (R1: FETCH 85->19MB; keep). 19200 % 8 == 0.
    int bid = blockIdx.x;
    int swz = (bid & (NXCD_-1)) * (NWG_/NXCD_) + (bid >> 3);

    int base   = swz * OPB_;            // block's first flat output
    int n      = base / DHW_;           // wave-uniform (512 | DHW_)
    int local0 = (base % DHW_) + threadIdx.x;

    const float* m = mat + n * 12;
    const float* s = src + n * DHW_;

    float res[2];
    // Two independent outputs per thread: flat idx local0 and local0+256.
    // Both chunks keep consecutive lanes at stride 4B (full line density —
    // the R2 lesson), while halving per-wave fixed cost and giving the
    // scheduler 16 independent gathers to keep in flight.
    #pragma unroll
    for (int j = 0; j < 2; ++j) {
        int local = local0 + j * 256;

        int w = local % W_;
        int t = local / W_;
        int h = t % H_;
        int d = t / H_;

        float x = -1.0f + w * (2.0f / (W_ - 1));
        float y = -1.0f + h * (2.0f / (H_ - 1));
        float z = -1.0f + d * (2.0f / (D_ - 1));

        float gx = m[0]*x + m[1]*y + m[2]*z  + m[3];
        float gy = m[4]*x + m[5]*y + m[6]*z  + m[7];
        float gz = m[8]*x + m[9]*y + m[10]*z + m[11];

        float ix = (gx + 1.0f) * (0.5f * (W_ - 1));
        float iy = (gy + 1.0f) * (0.5f * (H_ - 1));
        float iz = (gz + 1.0f) * (0.5f * (D_ - 1));

        float fx = floorf(ix), fy = floorf(iy), fz = floorf(iz);
        float wx = ix - fx, wy = iy - fy, wz = iz - fz;
        int x0 = (int)fx, y0 = (int)fy, z0 = (int)fz;

        float acc;
        bool interior = ((unsigned)x0 < (unsigned)(W_-1)) &
                        ((unsigned)y0 < (unsigned)(H_-1)) &
                        ((unsigned)z0 < (unsigned)(D_-1));

        if (__all(interior)) {
            // 2 base addresses; +1/+W_ fold into load offsets (4/640/644).
            const float* p = s + (z0 * H_ + y0) * W_ + x0;
            float v000 = p[0],        v001 = p[1];
            float v010 = p[W_],       v011 = p[W_ + 1];
            float v100 = p[HW_],      v101 = p[HW_ + 1];
            float v110 = p[HW_ + W_], v111 = p[HW_ + W_ + 1];
            float c00 = v000 + wx * (v001 - v000);
            float c01 = v010 + wx * (v011 - v010);
            float c10 = v100 + wx * (v101 - v100);
            float c11 = v110 + wx * (v111 - v110);
            float c0  = c00 + wy * (c01 - c00);
            float c1  = c10 + wy * (c11 - c10);
            acc = c0 + wz * (c1 - c0);
        } else {
            // Boundary path: clamp + zero-pad, exactly like the reference.
            acc = 0.0f;
            #pragma unroll
            for (int dz = 0; dz < 2; ++dz) {
                int  zi  = z0 + dz;
                bool vz  = (zi >= 0) & (zi < D_);
                int  zc  = min(max(zi, 0), D_ - 1);
                float wzz = dz ? wz : 1.0f - wz;
                #pragma unroll
                for (int dy = 0; dy < 2; ++dy) {
                    int  yi  = y0 + dy;
                    bool vzy = vz & (yi >= 0) & (yi < H_);
                    int  yc  = min(max(yi, 0), H_ - 1);
                    float wzy = wzz * (dy ? wy : 1.0f - wy);
                    int rowoff = (zc * H_ + yc) * W_;
                    #pragma unroll
                    for (int dx = 0; dx < 2; ++dx) {
                        int  xi = x0 + dx;
                        bool v  = vzy & (xi >= 0) & (xi < W_);
                        int  xc = min(max(xi, 0), W_ - 1);
                        float ww = wzy * (dx ? wx : 1.0f - wx);
                        float val = v ? s[rowoff + xc] : 0.0f;
                        acc += ww * val;
                    }
                }
            }
        }
        res[j] = acc;
    }

    out[n * DHW_ + local0]       = res[0];
    out[n * DHW_ + local0 + 256] = res[1];
}

extern "C" void kernel_launch(void* const* d_in, const int* in_sizes, int n_in,
                              void* d_out, int out_size, void* d_ws, size_t ws_size,
                              hipStream_t stream) {
    const float* src       = (const float*)d_in[0];
    const float* affine    = (const float*)d_in[1];
    const float* scale     = (const float*)d_in[2];
    const float* translate = (const float*)d_in[3];
    const float* shear     = (const float*)d_in[4];

    float* out     = (float*)d_out;
    float* mat_out = out + TOTAL_;   // tuple output #2: (N,3,4) flat

    build_mat_kernel<<<1, 64, 0, stream>>>(affine, scale, translate, shear, mat_out);
    affine_sample_kernel<<<NWG_, 256, 0, stream>>>(src, mat_out, out);
}